// Round 15
// baseline (90.745 us; speedup 1.0000x reference)
//
#include <hip/hip_runtime.h>

// Exponential smoothing: s[-1]=v0; s[j] = w*s[j-1] + (1-w)*x[j]; out[j]=s[j]
// w = sigmoid(smoothing_weight[h]).
// Round-15: 3-kernel PURE STREAMING pipeline (family switch after the
// single-pass sync family plateaued at ~62us, latency-bound at 3.4 TB/s):
//   K1: thread = (b, 16-step chunk c, f4-channel): fold zero-seed aggregate
//       A_c, write to agg (8 MiB). No sync of any kind.
//   K2: 16 blocks x 512 threads: per (b, float-channel) serial prefix over
//       the 256 chunk aggregates (L2/L3-resident), writes carry (8 MiB).
//   K3: thread = (b, c, f4-ch): seed = carry[c], scan 16 steps, NONTEMPORAL
//       store to out. NT keeps `out` OUT of L3 so `values` (128 MiB) stays
//       L3-resident for K1/K3 across kernels and timed replays (round-0's
//       re-read thrashed precisely because cached out-writes evicted values).
// No atomics, no polls, no barriers, no pinned regs, no LDS, no memsets.
// Fixed fold order => bit-deterministic.

namespace {

constexpr int Bt = 16;           // batch
constexpr int Tt = 4096;         // time
constexpr int HD4 = 128;         // float4 channels per (b,t)
constexpr int CL = 16;           // chunk length = per-thread steps
constexpr int NC = Tt / CL;      // 256 chunks per batch
constexpr int THREADS = 256;
constexpr int NBLK13 = Bt * NC * HD4 / THREADS;   // 2048 blocks for K1/K3

typedef float fvec4 __attribute__((ext_vector_type(4)));

__device__ __forceinline__ float sigmoidf_(float x) {
    return 1.0f / (1.0f + expf(-x));
}

// K1: zero-seed 16-step chunk aggregate per thread.
__global__ __launch_bounds__(THREADS) void k1_agg(
    const float4* __restrict__ values4, const float* __restrict__ sw,
    float4* __restrict__ agg4) {
    const int gt  = blockIdx.x * THREADS + threadIdx.x;
    const int ch4 = gt & (HD4 - 1);
    const int c   = (gt >> 7) & (NC - 1);
    const int b   = gt >> 15;
    const float w   = sigmoidf_(sw[ch4 >> 4]);
    const float omw = 1.0f - w;

    const float4* p = values4 + ((size_t)b * Tt + (size_t)c * CL) * HD4 + ch4;
    float4 A = make_float4(0.f, 0.f, 0.f, 0.f);
    #pragma unroll
    for (int u = 0; u < CL; ++u) {
        float4 xv = p[(size_t)u * HD4];
        A.x = fmaf(w, A.x, omw * xv.x);
        A.y = fmaf(w, A.y, omw * xv.y);
        A.z = fmaf(w, A.z, omw * xv.z);
        A.w = fmaf(w, A.w, omw * xv.w);
    }
    agg4[((size_t)c * Bt + b) * HD4 + ch4] = A;
}

// K2: serial carry prefix across chunks. One block per batch, thread =
// scalar float channel. carry[c] = state ENTERING chunk c.
__global__ __launch_bounds__(512) void k2_carry(
    const float* __restrict__ sw, const float* __restrict__ v0f,
    const float* __restrict__ aggf, float* __restrict__ carryf) {
    const int b   = blockIdx.x;
    const int tid = threadIdx.x;          // 0..511 float channel
    const float w = sigmoidf_(sw[tid >> 6]);
    float W16 = w * w;  W16 *= W16;  W16 *= W16;  W16 *= W16;   // w^16

    float s = v0f[tid];
    for (int c = 0; c < NC; ++c) {
        const size_t off = ((size_t)c * Bt + b) * 512 + tid;
        carryf[off] = s;
        s = fmaf(W16, s, aggf[off]);
    }
}

// K3: final scan seeded with carry; nontemporal store to out.
__global__ __launch_bounds__(THREADS) void k3_scan(
    const float4* __restrict__ values4, const float* __restrict__ sw,
    const float4* __restrict__ carry4, float4* __restrict__ out4) {
    const int gt  = blockIdx.x * THREADS + threadIdx.x;
    const int ch4 = gt & (HD4 - 1);
    const int c   = (gt >> 7) & (NC - 1);
    const int b   = gt >> 15;
    const float w   = sigmoidf_(sw[ch4 >> 4]);
    const float omw = 1.0f - w;

    const size_t base = ((size_t)b * Tt + (size_t)c * CL) * HD4 + ch4;
    const float4* p = values4 + base;
    fvec4* q = (fvec4*)(out4 + base);
    float4 s = carry4[((size_t)c * Bt + b) * HD4 + ch4];
    #pragma unroll
    for (int u = 0; u < CL; ++u) {
        float4 xv = p[(size_t)u * HD4];
        s.x = fmaf(w, s.x, omw * xv.x);
        s.y = fmaf(w, s.y, omw * xv.y);
        s.z = fmaf(w, s.z, omw * xv.z);
        s.w = fmaf(w, s.w, omw * xv.w);
        fvec4 sn = {s.x, s.y, s.z, s.w};
        __builtin_nontemporal_store(sn, q + (size_t)u * HD4);
    }
}

}  // namespace

extern "C" void kernel_launch(void* const* d_in, const int* in_sizes, int n_in,
                              void* d_out, int out_size, void* d_ws, size_t ws_size,
                              hipStream_t stream) {
    const float4* values4 = (const float4*)d_in[0];  // [16, 4096, 8, 64] f32
    const float*  sw      = (const float*)d_in[1];   // [8, 1]
    const float*  v0f     = (const float*)d_in[2];   // [1, 1, 8, 64] = 512 f32
    float4* out4 = (float4*)d_out;

    // Workspace: agg (NC*Bt*512 f32 = 8 MiB) + carry (8 MiB). No init needed:
    // K1 fully writes agg before K2 reads; K2 fully writes carry before K3.
    float* aggf   = (float*)d_ws;
    float* carryf = aggf + (size_t)NC * Bt * 512;

    k1_agg <<<dim3(NBLK13), dim3(THREADS), 0, stream>>>(values4, sw,
                                                        (float4*)aggf);
    k2_carry<<<dim3(Bt), dim3(512), 0, stream>>>(sw, v0f, aggf, carryf);
    k3_scan <<<dim3(NBLK13), dim3(THREADS), 0, stream>>>(values4, sw,
                                                         (const float4*)carryf,
                                                         out4);
}

// Round 18
// 79.652 us; speedup vs baseline: 1.1393x; 1.1393x over previous
//
#include <hip/hip_runtime.h>

// Exponential smoothing: s[-1]=v0; s[j] = w*s[j-1] + (1-w)*x[j]; out[j]=s[j]
// w = sigmoid(smoothing_weight[h]).
// Round-18 = round-16 resubmitted again (two container flakes in a row; the
// error occurs before the kernel is pushed, so it carries no kernel signal).
// Single-pass, LDS-staged (spill-proof), occupancy-maxed:
//   - 1024-thread blocks, CL=32 chunk staged in 64 KiB LDS: per-thread state
//     is tiny (TS=4), so the register allocator cannot spill chunk data
//     (rounds 11/12/14 all spilled pinned register chunks)
//   - 16 waves/block x 2 blocks/CU = 32 waves/CU (100% of the wave cap)
//   - walk: serial poll-and-fold by threads 0..511, <=15 remainder + <=7
//     supergroup polls (SG=16); sg producers publish BEFORE polling sgs
//   - relaxed agent atomics + 0xFFFFFFFF sentinel only (no fences)
//   - NT stores for out => values stays L3-resident across timed replays
// Ticket keeps dependency-order = dispatch-order => progress always.
// Fixed-order folds => bit-deterministic.

namespace {

constexpr int Bt   = 16;          // batch
constexpr int Tt   = 4096;        // time
constexpr int HD4  = 128;         // float4 channels per (b,t)
constexpr int CL   = 32;          // chunk length
constexpr int NGRP = 8;           // time-groups per chunk
constexpr int TS   = CL / NGRP;   // 4 steps per thread
constexpr int NC   = Tt / CL;     // 128 chunks per batch
constexpr int NBLK = NC * Bt;     // 2048
constexpr int NTHR = NGRP * HD4;  // 1024 threads
constexpr int SG   = 16;          // chunks per supergroup
constexpr int NSG  = NC / SG;     // 8
constexpr unsigned SENT = 0xFFFFFFFFu;

typedef float fvec4 __attribute__((ext_vector_type(4)));

__device__ __forceinline__ float sigmoidf_(float x) {
    return 1.0f / (1.0f + expf(-x));
}

__device__ __forceinline__ unsigned ld_relaxed(const unsigned* p) {
    return __hip_atomic_load(p, __ATOMIC_RELAXED, __HIP_MEMORY_SCOPE_AGENT);
}

__device__ __forceinline__ float poll1(const unsigned* p) {
    unsigned u = ld_relaxed(p);
    while (u == SENT) {
        __builtin_amdgcn_s_sleep(2);
        u = ld_relaxed(p);
    }
    return __uint_as_float(u);
}

__device__ __forceinline__ void store1(float* p, float v) {
    __hip_atomic_store(p, v, __ATOMIC_RELAXED, __HIP_MEMORY_SCOPE_AGENT);
}

__device__ __forceinline__ void store4(float* p, const float4& v) {
    store1(p + 0, v.x); store1(p + 1, v.y);
    store1(p + 2, v.z); store1(p + 3, v.w);
}

__global__ __launch_bounds__(NTHR, 8) void ema_onepass(
    const float4* __restrict__ values4, const float* __restrict__ sw,
    const float* __restrict__ v0f, float4* __restrict__ out4,
    float* __restrict__ aggf, float* __restrict__ sgf,
    int* __restrict__ ticket) {

    __shared__ float4 s_x[CL][HD4];      // 64 KiB chunk stage
    __shared__ float4 s_A[NGRP][HD4];    // 8 KiB group partial aggregates
    __shared__ float4 s_Ab[HD4];         // 2 KiB block aggregate
    __shared__ float  s_carry[512];      // 2 KiB carry (scalar channels)
    __shared__ int s_vid;

    const int tid = threadIdx.x;
    if (tid == 0) s_vid = atomicAdd(ticket, 1);
    __syncthreads();
    const int vid = s_vid;
    const int b = vid & (Bt - 1);
    const int c = vid >> 4;              // chunk; deps have lower vid
    const int ch = tid & (HD4 - 1);
    const int g  = tid >> 7;             // time-group 0..7, wave-uniform

    const float w   = sigmoidf_(sw[ch >> 4]);
    const float omw = 1.0f - w;
    const float W4  = (w * w) * (w * w);              // w^4 (group width)

    // Stage my 4 time-steps -> LDS; fold zero-seed group partial.
    const size_t rowbase =
        ((size_t)b * Tt + (size_t)c * CL + (size_t)g * TS) * HD4 + ch;
    const float4* p = values4 + rowbase;
    float4 A = make_float4(0.f, 0.f, 0.f, 0.f);
    #pragma unroll
    for (int u = 0; u < TS; ++u) {
        float4 xv = p[(size_t)u * HD4];
        s_x[g * TS + u][ch] = xv;
        A.x = fmaf(w, A.x, omw * xv.x);
        A.y = fmaf(w, A.y, omw * xv.y);
        A.z = fmaf(w, A.z, omw * xv.z);
        A.w = fmaf(w, A.w, omw * xv.w);
    }
    s_A[g][ch] = A;
    __syncthreads();   // barrier 1

    // Last group folds block aggregate (8 partials, w^4 steps) and publishes.
    if (g == NGRP - 1) {
        float4 t = s_A[0][ch];
        #pragma unroll
        for (int j = 1; j < NGRP; ++j) {
            float4 Aj = (j == NGRP - 1) ? A : s_A[j][ch];
            t.x = fmaf(W4, t.x, Aj.x);
            t.y = fmaf(W4, t.y, Aj.y);
            t.z = fmaf(W4, t.z, Aj.z);
            t.w = fmaf(W4, t.w, Aj.w);
        }
        s_Ab[ch] = t;
        store4(aggf + ((size_t)c * Bt + b) * 512 + 4 * ch, t);
    }
    __syncthreads();   // barrier 2

    // ---- Carry walk: threads 0..511, one float channel each ----
    if (tid < 512) {
        const float ws = sigmoidf_(sw[tid >> 6]);
        float Wcs = ws * ws;
        #pragma unroll
        for (int i = 0; i < 4; ++i) Wcs = Wcs * Wcs;           // w^32 = w^CL
        float WSGs = Wcs;
        #pragma unroll
        for (int i = 0; i < 4; ++i) WSGs = WSGs * WSGs;        // w^512

        const unsigned* au = (const unsigned*)aggf;
        const unsigned* su = (const unsigned*)sgf;
        const int mf  = c >> 4;          // complete supergroups (SG=16)
        const int k0  = mf << 4;
        const int rem = c - k0;          // 0..15

        // Phase 1: remainder scan R (seed 0), serial poll-and-fold.
        float R = 0.0f;
        #pragma unroll
        for (int j = 0; j < SG - 1; ++j) {
            if (k0 + j < c) {
                float av = poll1(au + ((size_t)(k0 + j) * Bt + b) * 512 + tid);
                R = fmaf(Wcs, R, av);
            }
        }

        // Phase 2: supergroup producer publishes immediately (local deps).
        if ((c & (SG - 1)) == SG - 1) {
            float ab = ((const float*)s_Ab)[tid];
            store1(sgf + ((size_t)mf * Bt + b) * 512 + tid,
                   fmaf(Wcs, R, ab));
            asm volatile("" ::: "memory");
        }

        // Phase 3: supergroup prefix P (seed v0), serial poll-and-fold.
        float P = v0f[tid];
        #pragma unroll
        for (int j = 0; j < NSG - 1; ++j) {
            if (j < mf) {
                float svv = poll1(su + ((size_t)j * Bt + b) * 512 + tid);
                P = fmaf(WSGs, P, svv);
            }
        }

        // carry = Wc^rem * P + R   (rem in 0..15)
        float Wr = 1.0f, pw = Wcs;
        if (rem & 1) Wr *= pw;  pw *= pw;
        if (rem & 2) Wr *= pw;  pw *= pw;
        if (rem & 4) Wr *= pw;  pw *= pw;
        if (rem & 8) Wr *= pw;
        s_carry[tid] = fmaf(Wr, P, R);
    }
    __syncthreads();   // barrier 3

    // Group seed: carry + fold of group partials < g (w^4 steps).
    float4 s;
    s.x = s_carry[4 * ch + 0];
    s.y = s_carry[4 * ch + 1];
    s.z = s_carry[4 * ch + 2];
    s.w = s_carry[4 * ch + 3];
    #pragma unroll
    for (int j = 0; j < NGRP - 1; ++j) {
        if (j < g) {
            float4 Aj = s_A[j][ch];
            s.x = fmaf(W4, s.x, Aj.x);
            s.y = fmaf(W4, s.y, Aj.y);
            s.z = fmaf(W4, s.z, Aj.z);
            s.w = fmaf(W4, s.w, Aj.w);
        }
    }

    // Final scan from LDS; nontemporal stream out.
    fvec4* q = (fvec4*)(out4 + rowbase);
    #pragma unroll
    for (int u = 0; u < TS; ++u) {
        float4 xv = s_x[g * TS + u][ch];
        s.x = fmaf(w, s.x, omw * xv.x);
        s.y = fmaf(w, s.y, omw * xv.y);
        s.z = fmaf(w, s.z, omw * xv.z);
        s.w = fmaf(w, s.w, omw * xv.w);
        fvec4 sn = {s.x, s.y, s.z, s.w};
        __builtin_nontemporal_store(sn, q + (size_t)u * HD4);
    }
}

}  // namespace

extern "C" void kernel_launch(void* const* d_in, const int* in_sizes, int n_in,
                              void* d_out, int out_size, void* d_ws, size_t ws_size,
                              hipStream_t stream) {
    const float4* values4 = (const float4*)d_in[0];  // [16, 4096, 8, 64] f32
    const float*  sw      = (const float*)d_in[1];   // [8, 1]
    const float*  v0f     = (const float*)d_in[2];   // [1, 1, 8, 64] = 512 f32
    float4* out4 = (float4*)d_out;

    const size_t aggFloats = (size_t)NC * Bt * 512;   // 4 MiB
    const size_t sgFloats  = (size_t)NSG * Bt * 512;  // 256 KiB
    float* aggf   = (float*)d_ws;
    float* sgf    = aggf + aggFloats;
    int*   ticket = (int*)(sgf + sgFloats);

    (void)hipMemsetAsync(aggf, 0xFF, (aggFloats + sgFloats) * sizeof(float), stream);
    (void)hipMemsetAsync(ticket, 0, sizeof(int), stream);

    ema_onepass<<<dim3(NBLK), dim3(NTHR), 0, stream>>>(values4, sw, v0f, out4,
                                                       aggf, sgf, ticket);
}

// Round 19
// 73.151 us; speedup vs baseline: 1.2405x; 1.0889x over previous
//
#include <hip/hip_runtime.h>

// Exponential smoothing: s[-1]=v0; s[j] = w*s[j-1] + (1-w)*x[j]; out[j]=s[j]
// w = sigmoid(smoothing_weight[h]).
// Round-19: TWO-KERNEL ZERO-SYNC design. After 8 single-pass variants all
// landed 62-80us (ticket+barriers+poll machinery costs ~27us regardless of
// geometry), remove the machinery entirely:
//   K1: thread=(b,c,ch4) folds CL=32 chunk aggregate -> agg (4 MiB). Pure
//       stream, no sync.
//   K2: same mapping; carry = per-thread fold of agg[0..c) with PLAIN loads
//       (kernel boundary = visibility; no polls so all loads pipeline);
//       then stream-scan values (each element read once, nothing held in
//       registers across phases -> nothing to spill) and NT-store out.
// vs round-3 (72us, same shape): NT stores keep `out` out of L3 so K2's
// values re-read is L3-served; 4 blocks/CU fully-resident grids; no
// launch_bounds register pressure. No atomics, no memsets, no barriers.
// Fixed fold order => bit-deterministic.

namespace {

constexpr int Bt  = 16;          // batch
constexpr int Tt  = 4096;        // time
constexpr int HD4 = 128;         // float4 channels per (b,t)
constexpr int CL  = 32;          // chunk length
constexpr int NC  = Tt / CL;     // 128 chunks per batch
constexpr int THR = 256;
constexpr int NBLK = Bt * NC * HD4 / THR;   // 1024 blocks

typedef float fvec4 __attribute__((ext_vector_type(4)));

__device__ __forceinline__ float sigmoidf_(float x) {
    return 1.0f / (1.0f + expf(-x));
}

// K1: zero-seed chunk aggregate, one thread per (b, c, float4-channel).
__global__ __launch_bounds__(THR) void k1_agg(
    const float4* __restrict__ values4, const float* __restrict__ sw,
    float4* __restrict__ agg4) {
    const int gt  = blockIdx.x * THR + threadIdx.x;
    const int ch4 = gt & (HD4 - 1);
    const int c   = (gt >> 7) & (NC - 1);
    const int b   = gt >> 14;
    const float w   = sigmoidf_(sw[ch4 >> 4]);
    const float omw = 1.0f - w;

    const float4* p = values4 + ((size_t)b * Tt + (size_t)c * CL) * HD4 + ch4;
    float4 A = make_float4(0.f, 0.f, 0.f, 0.f);
    #pragma unroll
    for (int u = 0; u < CL; ++u) {
        float4 xv = p[(size_t)u * HD4];
        A.x = fmaf(w, A.x, omw * xv.x);
        A.y = fmaf(w, A.y, omw * xv.y);
        A.z = fmaf(w, A.z, omw * xv.z);
        A.w = fmaf(w, A.w, omw * xv.w);
    }
    agg4[((size_t)c * Bt + b) * HD4 + ch4] = A;
}

// K2: carry = fold of agg[0..c) (plain loads, fully pipelined), then
// stream-scan the chunk and NT-store out.
__global__ __launch_bounds__(THR) void k2_scan(
    const float4* __restrict__ values4, const float* __restrict__ sw,
    const float4* __restrict__ v04, const float4* __restrict__ agg4,
    float4* __restrict__ out4) {
    const int gt  = blockIdx.x * THR + threadIdx.x;
    const int ch4 = gt & (HD4 - 1);
    const int c   = (gt >> 7) & (NC - 1);
    const int b   = gt >> 14;
    const float w   = sigmoidf_(sw[ch4 >> 4]);
    const float omw = 1.0f - w;
    float W32 = w * w;
    #pragma unroll
    for (int i = 0; i < 4; ++i) W32 *= W32;   // w^32 = w^CL

    // Carry: s = v0; for k<c: s = W32*s + A_k.  Plain loads, unrolled for ILP.
    float4 s = v04[ch4];
    const float4* a = agg4 + b * HD4 + ch4;
    #pragma unroll 4
    for (int k = 0; k < c; ++k) {
        float4 A = a[(size_t)k * (Bt * HD4)];
        s.x = fmaf(W32, s.x, A.x);
        s.y = fmaf(W32, s.y, A.y);
        s.z = fmaf(W32, s.z, A.z);
        s.w = fmaf(W32, s.w, A.w);
    }

    // Stream scan: read each element once, NT-store out.
    const size_t base = ((size_t)b * Tt + (size_t)c * CL) * HD4 + ch4;
    const float4* p = values4 + base;
    fvec4* q = (fvec4*)(out4 + base);
    #pragma unroll
    for (int u = 0; u < CL; ++u) {
        float4 xv = p[(size_t)u * HD4];
        s.x = fmaf(w, s.x, omw * xv.x);
        s.y = fmaf(w, s.y, omw * xv.y);
        s.z = fmaf(w, s.z, omw * xv.z);
        s.w = fmaf(w, s.w, omw * xv.w);
        fvec4 sn = {s.x, s.y, s.z, s.w};
        __builtin_nontemporal_store(sn, q + (size_t)u * HD4);
    }
}

}  // namespace

extern "C" void kernel_launch(void* const* d_in, const int* in_sizes, int n_in,
                              void* d_out, int out_size, void* d_ws, size_t ws_size,
                              hipStream_t stream) {
    const float4* values4 = (const float4*)d_in[0];  // [16, 4096, 8, 64] f32
    const float*  sw      = (const float*)d_in[1];   // [8, 1]
    const float4* v04     = (const float4*)d_in[2];  // [1, 1, 8, 64]
    float4* out4 = (float4*)d_out;

    float4* agg4 = (float4*)d_ws;   // NC*Bt*HD4 float4 = 4 MiB; fully written
                                    // by K1 before K2 reads (kernel boundary)

    k1_agg <<<dim3(NBLK), dim3(THR), 0, stream>>>(values4, sw, agg4);
    k2_scan<<<dim3(NBLK), dim3(THR), 0, stream>>>(values4, sw, v04, agg4, out4);
}

// Round 21
// 70.587 us; speedup vs baseline: 1.2856x; 1.0363x over previous
//
#include <hip/hip_runtime.h>

// Exponential smoothing: s[-1]=v0; s[j] = w*s[j-1] + (1-w)*x[j]; out[j]=s[j]
// w = sigmoid(smoothing_weight[h]).
// Round-21 = round-20 resubmitted (container flake before kernel push; no
// bench signal). Single-pass; registers-not-LDS staging, sized to NOT spill.
// Spill ledger across the family: pinned>=32 data regs/thread ALWAYS spilled
// (r11/r12: VGPR=60, r14: VGPR=32); pinned<=16 never did (r10: VGPR=36).
//   - 1024-thread blocks, CL=32, TS=4 -> 16 pinned data regs + ~25 scratch
//   - LDS ~12.5 KiB (aggregates/carry only) -> 2 blocks/CU x 16 waves = 32
//     waves/CU (fixes round-18's 86 KiB LDS -> 1 block/CU failure)
//   - walk: serial poll-and-fold by threads 0..511 (<=15 remainder + <=7 sg,
//     SG=16); sg producers publish BEFORE polling sgs
//   - relaxed agent atomics + 0xFFFFFFFF sentinel only (no fences)
//   - NT stores for out => values stays L3-resident across timed replays
// Ticket keeps dependency-order = dispatch-order => progress always.
// Fixed-order folds => bit-deterministic.

namespace {

constexpr int Bt   = 16;          // batch
constexpr int Tt   = 4096;        // time
constexpr int HD4  = 128;         // float4 channels per (b,t)
constexpr int CL   = 32;          // chunk length
constexpr int NGRP = 8;           // time-groups per chunk
constexpr int TS   = CL / NGRP;   // 4 steps per thread
constexpr int NC   = Tt / CL;     // 128 chunks per batch
constexpr int NBLK = NC * Bt;     // 2048
constexpr int NTHR = NGRP * HD4;  // 1024 threads
constexpr int SG   = 16;          // chunks per supergroup
constexpr int NSG  = NC / SG;     // 8
constexpr unsigned SENT = 0xFFFFFFFFu;

typedef float fvec4 __attribute__((ext_vector_type(4)));

__device__ __forceinline__ float sigmoidf_(float x) {
    return 1.0f / (1.0f + expf(-x));
}

__device__ __forceinline__ unsigned ld_relaxed(const unsigned* p) {
    return __hip_atomic_load(p, __ATOMIC_RELAXED, __HIP_MEMORY_SCOPE_AGENT);
}

__device__ __forceinline__ float poll1(const unsigned* p) {
    unsigned u = ld_relaxed(p);
    while (u == SENT) {
        __builtin_amdgcn_s_sleep(2);
        u = ld_relaxed(p);
    }
    return __uint_as_float(u);
}

__device__ __forceinline__ void store1(float* p, float v) {
    __hip_atomic_store(p, v, __ATOMIC_RELAXED, __HIP_MEMORY_SCOPE_AGENT);
}

__device__ __forceinline__ void store4(float* p, const float4& v) {
    store1(p + 0, v.x); store1(p + 1, v.y);
    store1(p + 2, v.z); store1(p + 3, v.w);
}

__global__ __launch_bounds__(NTHR, 8) void ema_onepass(
    const float4* __restrict__ values4, const float* __restrict__ sw,
    const float* __restrict__ v0f, float4* __restrict__ out4,
    float* __restrict__ aggf, float* __restrict__ sgf,
    int* __restrict__ ticket) {

    __shared__ float4 s_A[NGRP][HD4];    // 8 KiB group partial aggregates
    __shared__ float4 s_Ab[HD4];         // 2 KiB block aggregate
    __shared__ float  s_carry[512];      // 2 KiB carry (scalar channels)
    __shared__ int s_vid;

    const int tid = threadIdx.x;
    if (tid == 0) s_vid = atomicAdd(ticket, 1);
    __syncthreads();
    const int vid = s_vid;
    const int b = vid & (Bt - 1);
    const int c = vid >> 4;              // chunk; deps have lower vid
    const int ch = tid & (HD4 - 1);
    const int g  = tid >> 7;             // time-group 0..7, wave-uniform

    const float w   = sigmoidf_(sw[ch >> 4]);
    const float omw = 1.0f - w;
    const float W4  = (w * w) * (w * w);              // w^4 (group width)

    // Load my 4 time-steps into registers; fold zero-seed group partial.
    const size_t rowbase =
        ((size_t)b * Tt + (size_t)c * CL + (size_t)g * TS) * HD4 + ch;
    const float4* p = values4 + rowbase;
    float4 x[TS];
    float4 A = make_float4(0.f, 0.f, 0.f, 0.f);
    #pragma unroll
    for (int u = 0; u < TS; ++u) {
        x[u] = p[(size_t)u * HD4];
        A.x = fmaf(w, A.x, omw * x[u].x);
        A.y = fmaf(w, A.y, omw * x[u].y);
        A.z = fmaf(w, A.z, omw * x[u].z);
        A.w = fmaf(w, A.w, omw * x[u].w);
    }
    // Pin the 16 data regs (anti-rematerialization; small enough to hold).
    #pragma unroll
    for (int u = 0; u < TS; ++u)
        asm volatile("" : "+v"(x[u].x), "+v"(x[u].y), "+v"(x[u].z), "+v"(x[u].w));

    s_A[g][ch] = A;
    __syncthreads();   // barrier 1

    // Last group folds block aggregate (8 partials, w^4 steps) and publishes.
    if (g == NGRP - 1) {
        float4 t = s_A[0][ch];
        #pragma unroll
        for (int j = 1; j < NGRP; ++j) {
            float4 Aj = (j == NGRP - 1) ? A : s_A[j][ch];
            t.x = fmaf(W4, t.x, Aj.x);
            t.y = fmaf(W4, t.y, Aj.y);
            t.z = fmaf(W4, t.z, Aj.z);
            t.w = fmaf(W4, t.w, Aj.w);
        }
        s_Ab[ch] = t;
        store4(aggf + ((size_t)c * Bt + b) * 512 + 4 * ch, t);
    }
    __syncthreads();   // barrier 2

    // ---- Carry walk: threads 0..511, one float channel each ----
    if (tid < 512) {
        const float ws = sigmoidf_(sw[tid >> 6]);
        float Wcs = ws * ws;
        #pragma unroll
        for (int i = 0; i < 4; ++i) Wcs = Wcs * Wcs;           // w^32 = w^CL
        float WSGs = Wcs;
        #pragma unroll
        for (int i = 0; i < 4; ++i) WSGs = WSGs * WSGs;        // w^512

        const unsigned* au = (const unsigned*)aggf;
        const unsigned* su = (const unsigned*)sgf;
        const int mf  = c >> 4;          // complete supergroups (SG=16)
        const int k0  = mf << 4;
        const int rem = c - k0;          // 0..15

        // Phase 1: remainder scan R (seed 0), serial poll-and-fold.
        float R = 0.0f;
        #pragma unroll
        for (int j = 0; j < SG - 1; ++j) {
            if (k0 + j < c) {
                float av = poll1(au + ((size_t)(k0 + j) * Bt + b) * 512 + tid);
                R = fmaf(Wcs, R, av);
            }
        }

        // Phase 2: supergroup producer publishes immediately (local deps).
        if ((c & (SG - 1)) == SG - 1) {
            float ab = ((const float*)s_Ab)[tid];
            store1(sgf + ((size_t)mf * Bt + b) * 512 + tid,
                   fmaf(Wcs, R, ab));
            asm volatile("" ::: "memory");
        }

        // Phase 3: supergroup prefix P (seed v0), serial poll-and-fold.
        float P = v0f[tid];
        #pragma unroll
        for (int j = 0; j < NSG - 1; ++j) {
            if (j < mf) {
                float svv = poll1(su + ((size_t)j * Bt + b) * 512 + tid);
                P = fmaf(WSGs, P, svv);
            }
        }

        // carry = Wc^rem * P + R   (rem in 0..15)
        float Wr = 1.0f, pw = Wcs;
        if (rem & 1) Wr *= pw;  pw *= pw;
        if (rem & 2) Wr *= pw;  pw *= pw;
        if (rem & 4) Wr *= pw;  pw *= pw;
        if (rem & 8) Wr *= pw;
        s_carry[tid] = fmaf(Wr, P, R);
    }
    __syncthreads();   // barrier 3

    // Group seed: carry + fold of group partials < g (w^4 steps).
    float4 s;
    s.x = s_carry[4 * ch + 0];
    s.y = s_carry[4 * ch + 1];
    s.z = s_carry[4 * ch + 2];
    s.w = s_carry[4 * ch + 3];
    #pragma unroll
    for (int j = 0; j < NGRP - 1; ++j) {
        if (j < g) {
            float4 Aj = s_A[j][ch];
            s.x = fmaf(W4, s.x, Aj.x);
            s.y = fmaf(W4, s.y, Aj.y);
            s.z = fmaf(W4, s.z, Aj.z);
            s.w = fmaf(W4, s.w, Aj.w);
        }
    }

    // Final scan from registers; nontemporal stream out.
    fvec4* q = (fvec4*)(out4 + rowbase);
    #pragma unroll
    for (int u = 0; u < TS; ++u) {
        s.x = fmaf(w, s.x, omw * x[u].x);
        s.y = fmaf(w, s.y, omw * x[u].y);
        s.z = fmaf(w, s.z, omw * x[u].z);
        s.w = fmaf(w, s.w, omw * x[u].w);
        fvec4 sn = {s.x, s.y, s.z, s.w};
        __builtin_nontemporal_store(sn, q + (size_t)u * HD4);
    }
}

}  // namespace

extern "C" void kernel_launch(void* const* d_in, const int* in_sizes, int n_in,
                              void* d_out, int out_size, void* d_ws, size_t ws_size,
                              hipStream_t stream) {
    const float4* values4 = (const float4*)d_in[0];  // [16, 4096, 8, 64] f32
    const float*  sw      = (const float*)d_in[1];   // [8, 1]
    const float*  v0f     = (const float*)d_in[2];   // [1, 1, 8, 64] = 512 f32
    float4* out4 = (float4*)d_out;

    const size_t aggFloats = (size_t)NC * Bt * 512;   // 4 MiB
    const size_t sgFloats  = (size_t)NSG * Bt * 512;  // 256 KiB
    float* aggf   = (float*)d_ws;
    float* sgf    = aggf + aggFloats;
    int*   ticket = (int*)(sgf + sgFloats);

    (void)hipMemsetAsync(aggf, 0xFF, (aggFloats + sgFloats) * sizeof(float), stream);
    (void)hipMemsetAsync(ticket, 0, sizeof(int), stream);

    ema_onepass<<<dim3(NBLK), dim3(NTHR), 0, stream>>>(values4, sw, v0f, out4,
                                                       aggf, sgf, ticket);
}

// Round 25
// 65.561 us; speedup vs baseline: 1.3841x; 1.0767x over previous
//
#include <hip/hip_runtime.h>

// Exponential smoothing: s[-1]=v0; s[j] = w*s[j-1] + (1-w)*x[j]; out[j]=s[j]
// w = sigmoid(smoothing_weight[h]).
// FINAL: round-14 verbatim — the measured best (61.9 us) across 3 design
// families and 15 measured variants. Single-pass chained scan; values read
// ONCE, out written ONCE.
//   - 1024-thread blocks, 8 groups x 128 float4-ch, TS=8 steps/thread
//   - grid 1024 blocks (CL=64, NC=64); hierarchical carry walk <=7 sg +
//     <=7 chunk polls (serial poll-and-fold, threads 0..511)
//   - inter-block comm: relaxed agent atomics + 0xFFFFFFFF sentinel only
//     (no fences -> no L2 wb/inv storms); sg producers publish before
//     polling sgs; ticket keeps dependency-order = dispatch-order
//   - fixed-order folds => bit-deterministic
// Known counters: VGPR=32 (x-block partially in L2-backed scratch), occ
// ~66%, FETCH ~70 MiB, WRITE ~140 MiB, ~3.5 TB/s effective. Remaining gap
// to the 43 us copy-roofline is the phase-serialized dependency critical
// path, shown insensitive to occupancy/spill/walk-shape interventions
// (rounds 16-21).

namespace {

constexpr int Bt   = 16;          // batch
constexpr int Tt   = 4096;        // time
constexpr int HD4  = 128;         // float4 channels per (b,t)
constexpr int CL   = 64;          // chunk length
constexpr int NGRP = 8;           // time-groups per chunk
constexpr int TS   = CL / NGRP;   // 8 steps per group
constexpr int NC   = Tt / CL;     // 64 chunks per batch
constexpr int NBLK = NC * Bt;     // 1024
constexpr int NTHR = NGRP * HD4;  // 1024 threads
constexpr unsigned SENT = 0xFFFFFFFFu;

typedef float fvec4 __attribute__((ext_vector_type(4)));

__device__ __forceinline__ float sigmoidf_(float x) {
    return 1.0f / (1.0f + expf(-x));
}

__device__ __forceinline__ unsigned ld_relaxed(const unsigned* p) {
    return __hip_atomic_load(p, __ATOMIC_RELAXED, __HIP_MEMORY_SCOPE_AGENT);
}

__device__ __forceinline__ float poll1(const unsigned* p) {
    unsigned u = ld_relaxed(p);
    while (u == SENT) {
        __builtin_amdgcn_s_sleep(2);
        u = ld_relaxed(p);
    }
    return __uint_as_float(u);
}

__device__ __forceinline__ void store1(float* p, float v) {
    __hip_atomic_store(p, v, __ATOMIC_RELAXED, __HIP_MEMORY_SCOPE_AGENT);
}

__device__ __forceinline__ void store4(float* p, const float4& v) {
    store1(p + 0, v.x); store1(p + 1, v.y);
    store1(p + 2, v.z); store1(p + 3, v.w);
}

__global__ __launch_bounds__(NTHR, 8) void ema_onepass(
    const float4* __restrict__ values4, const float* __restrict__ sw,
    const float* __restrict__ v0f, float4* __restrict__ out4,
    float* __restrict__ aggf, float* __restrict__ sgf,
    int* __restrict__ ticket) {

    __shared__ float4 s_A[NGRP][HD4];    // 16 KiB per-group partial aggs
    __shared__ float4 s_Ab[HD4];         // 2 KiB block aggregate
    __shared__ float4 s_carryv[HD4];     // 2 KiB carry
    __shared__ int s_vid;

    const int tid = threadIdx.x;
    if (tid == 0) s_vid = atomicAdd(ticket, 1);
    __syncthreads();
    const int vid = s_vid;
    const int b = vid & (Bt - 1);
    const int c = vid >> 4;              // chunk; deps have lower vid
    const int ch = tid & (HD4 - 1);
    const int g  = tid >> 7;             // time-group 0..7, wave-uniform

    const float w   = sigmoidf_(sw[ch >> 4]);
    const float omw = 1.0f - w;
    float W8 = w * w;  W8 = W8 * W8;  W8 = W8 * W8;       // w^8

    // Load my 8 time-steps into registers; fold zero-seed partial aggregate.
    const size_t chunkbase = ((size_t)b * Tt + (size_t)c * CL) * HD4 + ch;
    const float4* p = values4 + chunkbase + (size_t)g * TS * HD4;
    float4 x[TS];
    float4 A = make_float4(0.f, 0.f, 0.f, 0.f);
    #pragma unroll
    for (int u = 0; u < TS; ++u) {
        x[u] = p[(size_t)u * HD4];
        A.x = fmaf(w, A.x, omw * x[u].x);
        A.y = fmaf(w, A.y, omw * x[u].y);
        A.z = fmaf(w, A.z, omw * x[u].z);
        A.w = fmaf(w, A.w, omw * x[u].w);
    }
    // Pin the chunk (anti-rematerialization, rounds 5/6 lesson).
    #pragma unroll
    for (int u = 0; u < TS; ++u)
        asm volatile("" : "+v"(x[u].x), "+v"(x[u].y), "+v"(x[u].z), "+v"(x[u].w));

    s_A[g][ch] = A;
    __syncthreads();   // barrier 1

    // Last group folds the block aggregate (8 partials) and publishes.
    if (g == NGRP - 1) {
        float4 t = s_A[0][ch];
        #pragma unroll
        for (int j = 1; j < NGRP; ++j) {
            float4 Aj = (j == NGRP - 1) ? A : s_A[j][ch];
            t.x = fmaf(W8, t.x, Aj.x);
            t.y = fmaf(W8, t.y, Aj.y);
            t.z = fmaf(W8, t.z, Aj.z);
            t.w = fmaf(W8, t.w, Aj.w);
        }
        s_Ab[ch] = t;
        store4(aggf + (((size_t)c * Bt + b) * HD4 + ch) * 4, t);
    }
    __syncthreads();   // barrier 2

    // ---- Carry walk: threads 0..511, one float channel each ----
    if (tid < 512) {
        const float ws = sigmoidf_(sw[tid >> 6]);
        float Wcs = ws * ws;
        #pragma unroll
        for (int i = 0; i < 5; ++i) Wcs = Wcs * Wcs;           // w^64
        float WSGs = Wcs;
        #pragma unroll
        for (int i = 0; i < 3; ++i) WSGs = WSGs * WSGs;        // w^512

        const unsigned* au = (const unsigned*)aggf;
        const unsigned* su = (const unsigned*)sgf;
        const int mf  = c >> 3;          // complete supergroups (SG=8)
        const int k0  = mf << 3;
        const int rem = c - k0;          // 0..7

        // Phase 1: remainder scan R (seed 0), serial poll-and-fold.
        float R = 0.0f;
        #pragma unroll
        for (int j = 0; j < 7; ++j) {
            if (k0 + j < c) {
                float av = poll1(au + ((size_t)(k0 + j) * Bt + b) * (HD4 * 4) + tid);
                R = fmaf(Wcs, R, av);
            }
        }

        // Phase 2: supergroup producer publishes immediately (local deps).
        if ((c & 7) == 7) {
            float ab = ((const float*)s_Ab)[tid];
            store1(sgf + ((size_t)mf * Bt + b) * (HD4 * 4) + tid,
                   fmaf(Wcs, R, ab));
            asm volatile("" ::: "memory");
        }

        // Phase 3: supergroup prefix P (seed v0), serial poll-and-fold.
        float P = v0f[tid];
        #pragma unroll
        for (int j = 0; j < 7; ++j) {
            if (j < mf) {
                float svv = poll1(su + ((size_t)j * Bt + b) * (HD4 * 4) + tid);
                P = fmaf(WSGs, P, svv);
            }
        }

        // carry = Wc^rem * P + R   (rem in 0..7)
        float Wr = 1.0f, pw = Wcs;
        if (rem & 1) Wr *= pw;  pw *= pw;
        if (rem & 2) Wr *= pw;  pw *= pw;
        if (rem & 4) Wr *= pw;
        ((float*)s_carryv)[tid] = fmaf(Wr, P, R);
    }
    __syncthreads();   // barrier 3

    // Group seed: fold partial aggs of groups < g onto the carry.
    float4 s = s_carryv[ch];
    #pragma unroll
    for (int j = 0; j < NGRP - 1; ++j) {
        if (j < g) {
            float4 Aj = s_A[j][ch];
            s.x = fmaf(W8, s.x, Aj.x);
            s.y = fmaf(W8, s.y, Aj.y);
            s.z = fmaf(W8, s.z, Aj.z);
            s.w = fmaf(W8, s.w, Aj.w);
        }
    }

    // Final scan from registers; nontemporal stream out.
    fvec4* q = (fvec4*)(out4 + chunkbase + (size_t)g * TS * HD4);
    #pragma unroll
    for (int u = 0; u < TS; ++u) {
        s.x = fmaf(w, s.x, omw * x[u].x);
        s.y = fmaf(w, s.y, omw * x[u].y);
        s.z = fmaf(w, s.z, omw * x[u].z);
        s.w = fmaf(w, s.w, omw * x[u].w);
        fvec4 sn = {s.x, s.y, s.z, s.w};
        __builtin_nontemporal_store(sn, q + (size_t)u * HD4);
    }
}

}  // namespace

extern "C" void kernel_launch(void* const* d_in, const int* in_sizes, int n_in,
                              void* d_out, int out_size, void* d_ws, size_t ws_size,
                              hipStream_t stream) {
    const float4* values4 = (const float4*)d_in[0];  // [16, 4096, 8, 64] f32
    const float*  sw      = (const float*)d_in[1];   // [8, 1]
    const float*  v0f     = (const float*)d_in[2];   // [1, 1, 8, 64] = 512 f32
    float4* out4 = (float4*)d_out;

    const size_t aggFloats = (size_t)NC * Bt * HD4 * 4;        // 2 MiB
    const size_t sgFloats  = (size_t)(NC / 8) * Bt * HD4 * 4;  // 256 KiB
    float* aggf   = (float*)d_ws;
    float* sgf    = aggf + aggFloats;
    int*   ticket = (int*)(sgf + sgFloats);

    (void)hipMemsetAsync(aggf, 0xFF, (aggFloats + sgFloats) * sizeof(float), stream);
    (void)hipMemsetAsync(ticket, 0, sizeof(int), stream);

    ema_onepass<<<dim3(NBLK), dim3(NTHR), 0, stream>>>(values4, sw, v0f, out4,
                                                       aggf, sgf, ticket);
}